// Round 6
// baseline (6357.443 us; speedup 1.0000x reference)
//
#include <hip/hip_runtime.h>

#define BB 16
#define NN 2048
#define NITERS 100

// k = log2(e)/eps, eps = 0.05
#define K2E      28.853900817779268f
#define TWO_K2E  57.707801635558536f
#define INV_K2E  0.034657359027997264f
#define INV4K    0.008664339756999316f   // 1/(4k)
#define LMU      (-11.0f)                // log2(1/2048)

#if __has_builtin(__builtin_amdgcn_exp2f)
#define EXP2F(x) __builtin_amdgcn_exp2f(x)
#else
#define EXP2F(x) exp2f(x)
#endif

// Per-batch monotonic-epoch barrier: 16 blocks per batch, counter on its own
// 256B-spaced cacheline. Epoch e complete when cnt >= e*16. Agent-scope
// fences carry correctness regardless of block->XCD placement.
__device__ __forceinline__ void gbar(int* cnt, int ep) {
    __syncthreads();
    if (threadIdx.x == 0) {
        __threadfence();                      // release partial writes
        atomicAdd(cnt, 1);
        const int target = ep * 16;
        while (__hip_atomic_load(cnt, __ATOMIC_RELAXED, __HIP_MEMORY_SCOPE_AGENT) < target) {
            __builtin_amdgcn_s_sleep(1);
        }
        __threadfence();                      // acquire
    }
    __syncthreads();
}

// grid: 256 blocks x 1024 threads (1 block/CU). XCD-local batch grouping.
// ONE exchange per Sinkhorn iteration:
//   phase 1 (local): A_i for own 128 rows from block-local full B (sY4.w).
//   phase 2 (local): g-partials S_j^(blk) = sum_{own i} 2^(x_i·2ky_j + A_i)
//                    for ALL j — A_i register-resident, cross-wave via ds_add.
//   phase 3: write 8 KB partials, ONE barrier, gather 16 partials, reduce
//            redundantly, B_j -> sY4.w (LDS). A never leaves the block.
__global__ __launch_bounds__(1024) void emd_sinkhorn(
    const float* __restrict__ x, const float* __restrict__ y,
    float* __restrict__ Sp, int* __restrict__ cntb, float* __restrict__ out)
{
    __shared__ float4 sY4[NN];   // 32 KB: (2k*y0, 2k*y1, 2k*y2, B_j)
    __shared__ float  sS[NN];    // 8 KB: block-level g-partial accumulator

    const int tid   = threadIdx.x;
    const int lane  = tid & 63;
    const int wave  = tid >> 6;                   // 0..15
    const int batch = ((blockIdx.x & 7) << 1) | (blockIdx.x >> 7);
    const int sub   = (blockIdx.x >> 3) & 15;     // my 128-row slice
    const int base  = batch * NN;
    const int r0g   = base + sub * 128 + wave * 8;
    int* cnt = cntb + batch * 64;                 // 256 B spacing

    // ---- prologue: static table + B0 init, zero sS ----
    #pragma unroll
    for (int v = 0; v < 2; ++v) {
        const int p  = tid + v * 1024;
        const float* py = y + 3 * (size_t)(base + p);
        const float a = py[0], b = py[1], c = py[2];
        sY4[p] = make_float4(TWO_K2E * a, TWO_K2E * b, TWO_K2E * c,
                             -K2E * (a*a + b*b + c*c));
        sS[p] = 0.f;
    }
    float xr0[8], xr1[8], xr2[8];
    #pragma unroll
    for (int k = 0; k < 8; ++k) {
        const float* px = x + 3 * (size_t)(r0g + k);
        xr0[k] = px[0]; xr1[k] = px[1]; xr2[k] = px[2];
    }
    __syncthreads();

    int ep = 0;
    float Ak[8];

    for (int it = 0; it < NITERS; ++it) {
        // ===== phase 1: f for own 8 rows (full B local in sY4.w) =====
        {
            float acc[8] = {0,0,0,0,0,0,0,0};
            #pragma unroll 2
            for (int j0 = 0; j0 < NN; j0 += 64) {
                float4 t = sY4[j0 + lane];
                #pragma unroll
                for (int k = 0; k < 8; ++k)
                    acc[k] += EXP2F(fmaf(xr0[k], t.x, fmaf(xr1[k], t.y, fmaf(xr2[k], t.z, t.w))));
            }
            // multi-value butterfly; lane L<8 ends with row r(L) (bit0<->bit2 swap)
            const bool b0 = lane & 1, b1 = lane & 2, b2 = lane & 4;
            float v4[4], v2[2], v1;
            #pragma unroll
            for (int i = 0; i < 4; ++i) {
                float recv = __shfl_xor(b0 ? acc[i] : acc[i+4], 1, 64);
                v4[i] = (b0 ? acc[i+4] : acc[i]) + recv;
            }
            #pragma unroll
            for (int i = 0; i < 2; ++i) {
                float recv = __shfl_xor(b1 ? v4[i] : v4[i+2], 2, 64);
                v2[i] = (b1 ? v4[i+2] : v4[i]) + recv;
            }
            {
                float recv = __shfl_xor(b2 ? v2[0] : v2[1], 4, 64);
                v1 = (b2 ? v2[1] : v2[0]) + recv;
            }
            v1 += __shfl_xor(v1, 8, 64);
            v1 += __shfl_xor(v1, 16, 64);
            v1 += __shfl_xor(v1, 32, 64);
            float Aval = LMU - __log2f(v1);       // valid on lanes 0..7
            // redistribute to wave-uniform Ak[8] (r is an involution)
            #pragma unroll
            for (int k = 0; k < 8; ++k) {
                const int src = ((k & 1) << 2) | (k & 2) | ((k >> 2) & 1);
                Ak[k] = __shfl(Aval, src, 64);
            }
        }

        // ===== phase 2: g-partials over own 8 rows for ALL j =====
        // chunks of 256 j, wave-staggered to decorrelate ds_add contention
        for (int c = 0; c < 8; ++c) {
            const int cb = (((c + wave) & 7) << 8);
            float4 t0 = sY4[cb + lane];
            float4 t1 = sY4[cb + 64 + lane];
            float4 t2 = sY4[cb + 128 + lane];
            float4 t3 = sY4[cb + 192 + lane];
            float p0 = 0.f, p1 = 0.f, p2 = 0.f, p3 = 0.f;
            #pragma unroll
            for (int k = 0; k < 8; ++k) {
                p0 += EXP2F(fmaf(xr0[k], t0.x, fmaf(xr1[k], t0.y, fmaf(xr2[k], t0.z, Ak[k]))));
                p1 += EXP2F(fmaf(xr0[k], t1.x, fmaf(xr1[k], t1.y, fmaf(xr2[k], t1.z, Ak[k]))));
                p2 += EXP2F(fmaf(xr0[k], t2.x, fmaf(xr1[k], t2.y, fmaf(xr2[k], t2.z, Ak[k]))));
                p3 += EXP2F(fmaf(xr0[k], t3.x, fmaf(xr1[k], t3.y, fmaf(xr2[k], t3.z, Ak[k]))));
            }
            atomicAdd(&sS[cb + lane],        p0);
            atomicAdd(&sS[cb + 64  + lane],  p1);
            atomicAdd(&sS[cb + 128 + lane],  p2);
            atomicAdd(&sS[cb + 192 + lane],  p3);
        }
        __syncthreads();

        // ===== phase 3: one exchange =====
        const size_t off = (size_t)(it & 1) * (BB * 16 * NN)
                         + (size_t)(batch * 16 + sub) * NN;
        Sp[off + tid]        = sS[tid];
        Sp[off + tid + 1024] = sS[tid + 1024];
        gbar(cnt, ++ep);
        const size_t gof = (size_t)(it & 1) * (BB * 16 * NN)
                         + (size_t)batch * 16 * NN;
        #pragma unroll
        for (int v = 0; v < 2; ++v) {
            const int j = tid + v * 1024;
            float s = 0.f;
            #pragma unroll
            for (int b2 = 0; b2 < 16; ++b2) s += Sp[gof + b2 * NN + j];
            ((float*)&sY4[j])[3] = LMU - __log2f(s);   // new B_j
            sS[j] = 0.f;                               // re-zero for next iter
        }
        __syncthreads();
    }

    // ===== epilogue: sum_ij P_ij*C_ij; out = total/B =====
    {
        float x2k[8];
        #pragma unroll
        for (int k = 0; k < 8; ++k)
            x2k[k] = K2E * (xr0[k]*xr0[k] + xr1[k]*xr1[k] + xr2[k]*xr2[k]);
        float acc[8] = {0,0,0,0,0,0,0,0};
        for (int j0 = 0; j0 < NN; j0 += 64) {
            float4 t = sY4[j0 + lane];
            const float q = (t.x*t.x + t.y*t.y + t.z*t.z) * INV4K;  // k|y|^2
            #pragma unroll
            for (int k = 0; k < 8; ++k) {
                float d = fmaf(xr0[k], t.x, fmaf(xr1[k], t.y, fmaf(xr2[k], t.z, t.w)));
                float P = EXP2F(d + Ak[k]);                          // exp(logP)
                float C = fmaxf((x2k[k] + q - (d - t.w)) * INV_K2E, 0.f);
                acc[k] = fmaf(P, C, acc[k]);
            }
        }
        float s = 0.f;
        #pragma unroll
        for (int k = 0; k < 8; ++k) s += acc[k];
        #pragma unroll
        for (int m = 32; m > 0; m >>= 1) s += __shfl_xor(s, m, 64);
        if (lane == 0) sS[wave] = s;     // sS dead: reuse as wsum
        __syncthreads();
        if (tid == 0) {
            float bsum = 0.f;
            #pragma unroll
            for (int w = 0; w < 16; ++w) bsum += sS[w];
            atomicAdd(out, bsum * (1.0f / (float)BB));
        }
    }
}

extern "C" void kernel_launch(void* const* d_in, const int* in_sizes, int n_in,
                              void* d_out, int out_size, void* d_ws, size_t ws_size,
                              hipStream_t stream) {
    const float* x = (const float*)d_in[0];
    const float* y = (const float*)d_in[1];
    float* out = (float*)d_out;
    char* ws = (char*)d_ws;

    int*   cntb = (int*)ws;                    // 16 x 256 B
    float* Sp   = (float*)(ws + 4096);         // 2 x 16 x 16 x 2048 floats = 4 MB

    hipMemsetAsync(cntb, 0, 4096, stream);
    hipMemsetAsync(out, 0, sizeof(float), stream);

    void* args[] = {(void*)&x, (void*)&y, (void*)&Sp, (void*)&cntb, (void*)&out};
    hipLaunchCooperativeKernel((const void*)emd_sinkhorn, dim3(256), dim3(1024),
                               args, 0, stream);
}

// Round 7
// 4602.475 us; speedup vs baseline: 1.3813x; 1.3813x over previous
//
#include <hip/hip_runtime.h>

#define BB 16
#define NN 2048
#define NITERS 100

// k = log2(e)/eps, eps = 0.05
#define K2E      28.853900817779268f
#define TWO_K2E  57.707801635558536f
#define INV_K2E  0.034657359027997264f
#define INV4K    0.008664339756999316f   // 1/(4k)
#define LMU      (-11.0f)                // log2(1/2048)

#if __has_builtin(__builtin_amdgcn_exp2f)
#define EXP2F(x) __builtin_amdgcn_exp2f(x)
#else
#define EXP2F(x) exp2f(x)
#endif

// grid: 256 blocks x 1024 threads (1 block/CU). Each block hosts TWO 8-wave
// groups working on two different batches (m and m^1), anti-phased so one
// group's exchange latency hides under the other group's compute.
// R5 dataflow per group: f-pass over own 64 rows (full B local in sY.w),
// global A exchange, stage A->sX.w, g-pass over own 64 cols, B exchange,
// stage B->sY.w. Group barriers are LDS-local; the per-batch global barrier
// (32 groups) uses the R1-R5-verified fence/atomic/spin pattern in wave 0.
__global__ __launch_bounds__(1024) void emd_sinkhorn(
    const float* __restrict__ x, const float* __restrict__ y,
    float* __restrict__ Af, float* __restrict__ Bf,
    int* __restrict__ cntb, float* __restrict__ out)
{
    extern __shared__ float4 sT[];   // [grp][2][NN]: 128 KB (X|A, Y|B)
    __shared__ int   lgc[2];         // per-group monotonic arrive counter
    __shared__ int   lgf[2];         // per-group release flag (epoch)
    __shared__ float wsum[16];

    const int tid  = threadIdx.x;
    const int lane = tid & 63;
    const int wave = tid >> 6;        // 0..15
    const int grp  = wave >> 3;       // 0,1
    const int gw   = wave & 7;        // wave within group
    const int gtid = (gw << 6) | lane;

    const int blk   = blockIdx.x;
    const int m     = ((blk & 7) << 1) | (blk >> 7);   // XCD-local base batch
    const int batch = m ^ grp;                          // my group's batch
    const int slice = (((blk >> 3) & 15) << 1) | grp;   // 0..31 (64 rows each)
    const int base  = batch * NN;
    const int r0g   = base + slice * 64 + gw * 8;
    int* cnt = cntb + batch * 64;                       // 256 B spacing

    float4* sX = sT + grp * 2 * NN;   // (2k*x0,2k*x1,2k*x2, A_i)
    float4* sY = sX + NN;             // (2k*y0,2k*y1,2k*y2, B_j)

    if (tid < 2) { lgc[tid] = 0; lgf[tid] = 0; }
    __syncthreads();                  // only block-wide sync until epilogue

    // one-time anti-phase skew (~4.5 us) for odd batches
    if (batch & 1) {
        for (int i = 0; i < 20; ++i) __builtin_amdgcn_s_sleep(8);
    }

    // ---- prologue: group stages its own tables; B0 = -k|y|^2 ----
    #pragma unroll
    for (int v = 0; v < 4; ++v) {
        const int p = gtid + (v << 9);
        const float* px = x + 3 * (size_t)(base + p);
        sX[p] = make_float4(TWO_K2E*px[0], TWO_K2E*px[1], TWO_K2E*px[2], 0.f);
        const float* py = y + 3 * (size_t)(base + p);
        const float a = py[0], b = py[1], c = py[2];
        sY[p] = make_float4(TWO_K2E*a, TWO_K2E*b, TWO_K2E*c,
                            -K2E * (a*a + b*b + c*c));
    }
    float xr0[8], xr1[8], xr2[8], yc0[8], yc1[8], yc2[8];
    #pragma unroll
    for (int k = 0; k < 8; ++k) {
        const float* px = x + 3 * (size_t)(r0g + k);
        xr0[k] = px[0]; xr1[k] = px[1]; xr2[k] = px[2];
        const float* py = y + 3 * (size_t)(r0g + k);
        yc0[k] = py[0]; yc1[k] = py[1]; yc2[k] = py[2];
    }

    int lep = 0, ep = 0;
    float Ak[8];

    // group-local sync: every wave release-adds, all spin to lep*8
    #define GSYNC() do {                                                        \
        ++lep;                                                                  \
        if (lane == 0) {                                                        \
            __hip_atomic_fetch_add(&lgc[grp], 1, __ATOMIC_RELEASE,              \
                                   __HIP_MEMORY_SCOPE_WORKGROUP);               \
            while (__hip_atomic_load(&lgc[grp], __ATOMIC_ACQUIRE,               \
                                     __HIP_MEMORY_SCOPE_WORKGROUP) < lep * 8)   \
                __builtin_amdgcn_s_sleep(1);                                    \
        }                                                                       \
    } while (0)

    // per-batch global barrier: every wave release-adds (drains its global
    // stores); wave 0 waits group, fences, bumps batch counter, spins, fences,
    // releases LDS flag; other waves spin on the flag.
    #define GBAR() do {                                                         \
        ++lep; ++ep;                                                            \
        if (lane == 0)                                                          \
            __hip_atomic_fetch_add(&lgc[grp], 1, __ATOMIC_RELEASE,              \
                                   __HIP_MEMORY_SCOPE_WORKGROUP);               \
        if (gw == 0) {                                                          \
            if (lane == 0) {                                                    \
                while (__hip_atomic_load(&lgc[grp], __ATOMIC_ACQUIRE,           \
                                         __HIP_MEMORY_SCOPE_WORKGROUP) < lep*8) \
                    __builtin_amdgcn_s_sleep(1);                                \
                __threadfence();                                                \
                atomicAdd(cnt, 1);                                              \
                const int tgt = ep * 32;                                        \
                while (__hip_atomic_load(cnt, __ATOMIC_RELAXED,                 \
                                         __HIP_MEMORY_SCOPE_AGENT) < tgt)       \
                    __builtin_amdgcn_s_sleep(2);                                \
                __threadfence();                                                \
                __hip_atomic_store(&lgf[grp], lep, __ATOMIC_RELEASE,            \
                                   __HIP_MEMORY_SCOPE_WORKGROUP);               \
            }                                                                   \
        } else if (lane == 0) {                                                 \
            while (__hip_atomic_load(&lgf[grp], __ATOMIC_ACQUIRE,               \
                                     __HIP_MEMORY_SCOPE_WORKGROUP) < lep)       \
                __builtin_amdgcn_s_sleep(1);                                    \
        }                                                                       \
    } while (0)

    GSYNC();   // tables staged

    for (int it = 0; it < NITERS; ++it) {
        // ===== f-pass: A for own 8 rows/wave from sY (full B in .w) =====
        {
            float acc[8] = {0,0,0,0,0,0,0,0};
            #pragma unroll 2
            for (int j0 = 0; j0 < NN; j0 += 64) {
                float4 t = sY[j0 + lane];
                #pragma unroll
                for (int k = 0; k < 8; ++k)
                    acc[k] += EXP2F(fmaf(xr0[k], t.x, fmaf(xr1[k], t.y, fmaf(xr2[k], t.z, t.w))));
            }
            // multi-value butterfly; lane L<8 ends with row r(L) (bit0<->bit2)
            const bool b0 = lane & 1, b1 = lane & 2, b2 = lane & 4;
            float v4[4], v2[2], v1;
            #pragma unroll
            for (int i = 0; i < 4; ++i) {
                float recv = __shfl_xor(b0 ? acc[i] : acc[i+4], 1, 64);
                v4[i] = (b0 ? acc[i+4] : acc[i]) + recv;
            }
            #pragma unroll
            for (int i = 0; i < 2; ++i) {
                float recv = __shfl_xor(b1 ? v4[i] : v4[i+2], 2, 64);
                v2[i] = (b1 ? v4[i+2] : v4[i]) + recv;
            }
            {
                float recv = __shfl_xor(b2 ? v2[0] : v2[1], 4, 64);
                v1 = (b2 ? v2[1] : v2[0]) + recv;
            }
            v1 += __shfl_xor(v1, 8, 64);
            v1 += __shfl_xor(v1, 16, 64);
            v1 += __shfl_xor(v1, 32, 64);
            float Aval = LMU - __log2f(v1);       // lanes 0..7 valid
            if (lane < 8) {
                const int r = ((lane & 1) << 2) | (lane & 2) | ((lane >> 2) & 1);
                Af[r0g + r] = Aval;
            }
            #pragma unroll
            for (int k = 0; k < 8; ++k) {
                const int src = ((k & 1) << 2) | (k & 2) | ((k >> 2) & 1);
                Ak[k] = __shfl(Aval, src, 64);
            }
        }
        GBAR();                                   // A exchange
        #pragma unroll
        for (int v = 0; v < 4; ++v) {             // stage A -> sX.w
            const int p = gtid + (v << 9);
            ((float*)&sX[p])[3] = Af[base + p];
        }
        GSYNC();

        // ===== g-pass: B for own 8 cols/wave from sX (full A in .w) =====
        {
            float acc[8] = {0,0,0,0,0,0,0,0};
            #pragma unroll 2
            for (int j0 = 0; j0 < NN; j0 += 64) {
                float4 t = sX[j0 + lane];
                #pragma unroll
                for (int k = 0; k < 8; ++k)
                    acc[k] += EXP2F(fmaf(yc0[k], t.x, fmaf(yc1[k], t.y, fmaf(yc2[k], t.z, t.w))));
            }
            const bool b0 = lane & 1, b1 = lane & 2, b2 = lane & 4;
            float v4[4], v2[2], v1;
            #pragma unroll
            for (int i = 0; i < 4; ++i) {
                float recv = __shfl_xor(b0 ? acc[i] : acc[i+4], 1, 64);
                v4[i] = (b0 ? acc[i+4] : acc[i]) + recv;
            }
            #pragma unroll
            for (int i = 0; i < 2; ++i) {
                float recv = __shfl_xor(b1 ? v4[i] : v4[i+2], 2, 64);
                v2[i] = (b1 ? v4[i+2] : v4[i]) + recv;
            }
            {
                float recv = __shfl_xor(b2 ? v2[0] : v2[1], 4, 64);
                v1 = (b2 ? v2[1] : v2[0]) + recv;
            }
            v1 += __shfl_xor(v1, 8, 64);
            v1 += __shfl_xor(v1, 16, 64);
            v1 += __shfl_xor(v1, 32, 64);
            float Bval = LMU - __log2f(v1);
            if (lane < 8) {
                const int r = ((lane & 1) << 2) | (lane & 2) | ((lane >> 2) & 1);
                Bf[r0g + r] = Bval;
            }
        }
        GBAR();                                   // B exchange
        #pragma unroll
        for (int v = 0; v < 4; ++v) {             // stage B -> sY.w
            const int p = gtid + (v << 9);
            ((float*)&sY[p])[3] = Bf[base + p];
        }
        GSYNC();
    }

    // ===== epilogue: sum_ij P_ij*C_ij over own 64 rows; out = total/B =====
    {
        float x2k[8];
        #pragma unroll
        for (int k = 0; k < 8; ++k)
            x2k[k] = K2E * (xr0[k]*xr0[k] + xr1[k]*xr1[k] + xr2[k]*xr2[k]);
        float acc[8] = {0,0,0,0,0,0,0,0};
        for (int j0 = 0; j0 < NN; j0 += 64) {
            float4 t = sY[j0 + lane];
            const float q = (t.x*t.x + t.y*t.y + t.z*t.z) * INV4K;  // k|y|^2
            #pragma unroll
            for (int k = 0; k < 8; ++k) {
                float d = fmaf(xr0[k], t.x, fmaf(xr1[k], t.y, fmaf(xr2[k], t.z, t.w)));
                float P = EXP2F(d + Ak[k]);                          // exp(logP)
                float C = fmaxf((x2k[k] + q - (d - t.w)) * INV_K2E, 0.f);
                acc[k] = fmaf(P, C, acc[k]);
            }
        }
        float s = 0.f;
        #pragma unroll
        for (int k = 0; k < 8; ++k) s += acc[k];
        #pragma unroll
        for (int mm = 32; mm > 0; mm >>= 1) s += __shfl_xor(s, mm, 64);
        if (lane == 0) wsum[wave] = s;
        __syncthreads();
        if (tid == 0) {
            float bsum = 0.f;
            #pragma unroll
            for (int w = 0; w < 16; ++w) bsum += wsum[w];
            atomicAdd(out, bsum * (1.0f / (float)BB));
        }
    }
    #undef GSYNC
    #undef GBAR
}

extern "C" void kernel_launch(void* const* d_in, const int* in_sizes, int n_in,
                              void* d_out, int out_size, void* d_ws, size_t ws_size,
                              hipStream_t stream) {
    const float* x = (const float*)d_in[0];
    const float* y = (const float*)d_in[1];
    float* out = (float*)d_out;
    char* ws = (char*)d_ws;

    int*   cntb = (int*)ws;                                  // 16 x 256 B
    float* Af   = (float*)(ws + 4096);                       // 16*2048 = 128 KB
    float* Bf   = (float*)(ws + 4096 + (size_t)BB*NN*sizeof(float));

    hipMemsetAsync(cntb, 0, 4096, stream);
    hipMemsetAsync(out, 0, sizeof(float), stream);

    const size_t shmem = (size_t)2 * 2 * NN * sizeof(float4);  // 128 KB
    hipFuncSetAttribute((const void*)emd_sinkhorn,
                        hipFuncAttributeMaxDynamicSharedMemorySize, (int)shmem);

    void* args[] = {(void*)&x, (void*)&y, (void*)&Af, (void*)&Bf,
                    (void*)&cntb, (void*)&out};
    hipError_t e = hipLaunchCooperativeKernel((const void*)emd_sinkhorn,
                                              dim3(256), dim3(1024),
                                              args, shmem, stream);
    if (e != hipSuccess) {
        // capacity-safe fallback: 256 blocks on 256 CUs, 1 block/CU
        hipLaunchKernelGGL(emd_sinkhorn, dim3(256), dim3(1024), shmem, stream,
                           x, y, Af, Bf, cntb, out);
    }
}

// Round 8
// 3325.425 us; speedup vs baseline: 1.9118x; 1.3840x over previous
//
#include <hip/hip_runtime.h>

#define BB 16
#define NN 2048
#define NITERS 100

// k = log2(e)/eps, eps = 0.05
#define K2E      28.853900817779268f
#define TWO_K2E  57.707801635558536f
#define INV2K    0.017328679513998632f   // 1/(2k)
#define INV_K2E  0.034657359027997264f
#define INV4K    0.008664339756999316f   // 1/(4k)
#define LMU      (-11.0f)                // log2(1/2048)

#if __has_builtin(__builtin_amdgcn_exp2f)
#define EXP2F(x) __builtin_amdgcn_exp2f(x)
#else
#define EXP2F(x) exp2f(x)
#endif

// Sum-pass: rows = 8 uniform points (from LDS table u*, raw = u*INV2K),
// summed over this wave's j-half (1024 cols) of tables t0..t2 (2k-scaled)
// with dual addend td. Wave-pair partials combine via pcomb (LDS).
// Returns combined row-sum on lanes 0..7 (row index = rr involution).
__device__ __forceinline__ float sumpass(
    const float* __restrict__ u0, const float* __restrict__ u1,
    const float* __restrict__ u2,
    const float* __restrict__ t0, const float* __restrict__ t1,
    const float* __restrict__ t2, const float* __restrict__ td,
    int rloc, int jh, int lane, int w, float* pcomb)
{
    float xr0[8], xr1[8], xr2[8];
    #pragma unroll
    for (int k = 0; k < 8; ++k) {
        xr0[k] = u0[rloc + k] * INV2K;
        xr1[k] = u1[rloc + k] * INV2K;
        xr2[k] = u2[rloc + k] * INV2K;
    }
    float acc[8] = {0,0,0,0,0,0,0,0};
    const int jb = (jh << 10) + lane;
    #pragma unroll 2
    for (int s = 0; s < 16; ++s) {
        const int p = jb + (s << 6);
        const float a0 = t0[p], a1 = t1[p], a2 = t2[p], ad = td[p];
        #pragma unroll
        for (int k = 0; k < 8; ++k)
            acc[k] += EXP2F(fmaf(xr0[k], a0, fmaf(xr1[k], a1, fmaf(xr2[k], a2, ad))));
    }
    // multi-value butterfly (verified R3/R5); lanes<8 end with row rr
    const bool b0 = lane & 1, b1 = lane & 2, b2 = lane & 4;
    float v4[4], v2[2], v1;
    #pragma unroll
    for (int i = 0; i < 4; ++i) {
        float recv = __shfl_xor(b0 ? acc[i] : acc[i+4], 1, 64);
        v4[i] = (b0 ? acc[i+4] : acc[i]) + recv;
    }
    #pragma unroll
    for (int i = 0; i < 2; ++i) {
        float recv = __shfl_xor(b1 ? v4[i] : v4[i+2], 2, 64);
        v2[i] = (b1 ? v4[i+2] : v4[i]) + recv;
    }
    {
        float recv = __shfl_xor(b2 ? v2[0] : v2[1], 4, 64);
        v1 = (b2 ? v2[1] : v2[0]) + recv;
    }
    v1 += __shfl_xor(v1, 8, 64);
    v1 += __shfl_xor(v1, 16, 64);
    v1 += __shfl_xor(v1, 32, 64);
    const int rr = ((lane & 1) << 2) | (lane & 2) | ((lane >> 2) & 1);
    if (lane < 8) pcomb[w * 8 + rr] = v1;
    __syncthreads();
    float S = 0.f;
    if (lane < 8) S = v1 + pcomb[(w ^ 1) * 8 + rr];
    return S;
}

// Epilogue partial: sum_j P_ij*C_ij over own 8 rows x own j-half.
__device__ __forceinline__ float epil(
    const float* __restrict__ u0, const float* __restrict__ u1,
    const float* __restrict__ u2,
    const float* __restrict__ t0, const float* __restrict__ t1,
    const float* __restrict__ t2, const float* __restrict__ td,
    const float* __restrict__ sA, int rloc, int jh, int lane)
{
    float xr0[8], xr1[8], xr2[8], Ak[8], x2k[8];
    #pragma unroll
    for (int k = 0; k < 8; ++k) {
        xr0[k] = u0[rloc + k] * INV2K;
        xr1[k] = u1[rloc + k] * INV2K;
        xr2[k] = u2[rloc + k] * INV2K;
        Ak[k]  = sA[rloc + k];
        x2k[k] = K2E * (xr0[k]*xr0[k] + xr1[k]*xr1[k] + xr2[k]*xr2[k]);
    }
    float acc = 0.f;
    const int jb = (jh << 10) + lane;
    for (int s = 0; s < 16; ++s) {
        const int p = jb + (s << 6);
        const float a0 = t0[p], a1 = t1[p], a2 = t2[p], tb = td[p];
        const float q2 = (a0*a0 + a1*a1 + a2*a2) * INV4K;   // k|y|^2
        #pragma unroll
        for (int k = 0; k < 8; ++k) {
            float d = fmaf(xr0[k], a0, fmaf(xr1[k], a1, fmaf(xr2[k], a2, tb)));
            float P = EXP2F(d + Ak[k]);                       // exp(logP)
            float C = fmaxf((x2k[k] + q2 - (d - tb)) * INV_K2E, 0.f);
            acc = fmaf(P, C, acc);
        }
    }
    return acc;
}

// grid: 256 blocks x 1024 threads (1 block/CU). pair = blk&7 -> XCD-local:
// 32 blocks of batch pair (2p, 2p+1) on XCD p's 32 CUs. Deterministic
// software pipeline: every global-barrier wait has a full compute phase
// between the corresponding posts and the wait -> barrier pre-satisfied.
__global__ __launch_bounds__(1024) void emd_sinkhorn(
    const float* __restrict__ x, const float* __restrict__ y,
    float* __restrict__ Af, float* __restrict__ Bf,
    int* __restrict__ cntb, float* __restrict__ out)
{
    extern __shared__ float S[];     // 16*NN floats = 128 KB
    __shared__ float pcomb[16 * 8];
    __shared__ float wsum[16];

    const int tid  = threadIdx.x;
    const int lane = tid & 63;
    const int w    = tid >> 6;        // 0..15
    const int pr   = w >> 1;          // wave-pair 0..7
    const int jh   = w & 1;           // j-half
    const int blk  = blockIdx.x;
    const int pair = blk & 7;         // = XCD id under round-robin
    const int q    = blk >> 3;        // 0..31: row-slice within pair
    const int b0   = pair * 2, b1 = b0 + 1;
    const int base0 = b0 * NN, base1 = b1 * NN;
    const int rloc  = q * 64 + pr * 8;      // within-batch row base
    int* c0 = cntb + b0 * 64;
    int* c1 = cntb + b1 * 64;

    // LDS carve: per batch 8 slots of NN floats
    float *sy00 = S,            *sy10 = S +  1*NN, *sy20 = S +  2*NN;
    float *sx00 = S +  3*NN,    *sx10 = S +  4*NN, *sx20 = S +  5*NN;
    float *sA0  = S +  6*NN,    *sB0  = S +  7*NN;
    float *sy01 = S +  8*NN,    *sy11 = S +  9*NN, *sy21 = S + 10*NN;
    float *sx01 = S + 11*NN,    *sx11 = S + 12*NN, *sx21 = S + 13*NN;
    float *sA1  = S + 14*NN,    *sB1  = S + 15*NN;

    // ---- prologue: stage 2k-scaled tables; B0 = -k|y|^2 (local, no barrier) ----
    #pragma unroll
    for (int v = 0; v < 2; ++v) {
        const int p = tid + (v << 10);
        {
            const float* px = x + 3 * (size_t)(base0 + p);
            sx00[p] = TWO_K2E * px[0]; sx10[p] = TWO_K2E * px[1]; sx20[p] = TWO_K2E * px[2];
            const float* py = y + 3 * (size_t)(base0 + p);
            const float a = py[0], b = py[1], c = py[2];
            sy00[p] = TWO_K2E * a; sy10[p] = TWO_K2E * b; sy20[p] = TWO_K2E * c;
            sB0[p]  = -K2E * (a*a + b*b + c*c);
        }
        {
            const float* px = x + 3 * (size_t)(base1 + p);
            sx01[p] = TWO_K2E * px[0]; sx11[p] = TWO_K2E * px[1]; sx21[p] = TWO_K2E * px[2];
            const float* py = y + 3 * (size_t)(base1 + p);
            const float a = py[0], b = py[1], c = py[2];
            sy01[p] = TWO_K2E * a; sy11[p] = TWO_K2E * b; sy21[p] = TWO_K2E * c;
            sB1[p]  = -K2E * (a*a + b*b + c*c);
        }
    }
    __syncthreads();

    const int rr = ((lane & 1) << 2) | (lane & 2) | ((lane >> 2) & 1);

    #define POST(c) do { __syncthreads();                                       \
        if (tid == 0) { __threadfence(); atomicAdd((c), 1); } } while (0)

    #define WAITB(c, tgt) do { __syncthreads();                                 \
        if (tid == 0) {                                                         \
            while (__hip_atomic_load((c), __ATOMIC_RELAXED,                     \
                                     __HIP_MEMORY_SCOPE_AGENT) < (tgt))         \
                __builtin_amdgcn_s_sleep(2);                                    \
            __threadfence();                                                    \
        }                                                                       \
        __syncthreads(); } while (0)

    for (int it = 0; it < NITERS; ++it) {
        // ---- fA0: f for batch0 (uses sB0) ----
        {
            float Sc = sumpass(sx00, sx10, sx20, sy00, sy10, sy20, sB0,
                               rloc, jh, lane, w, pcomb);
            if (lane < 8 && jh == 0) Af[base0 + rloc + rr] = LMU - __log2f(Sc);
        }
        POST(c0);
        // ---- stage B1 of previous iteration (hidden behind fA0) ----
        if (it > 0) {
            WAITB(c1, 64 * it);
            ((float2*)sB1)[tid] = ((const float2*)(Bf + base1))[tid];
            __syncthreads();
        }
        // ---- fA1 ----
        {
            float Sc = sumpass(sx01, sx11, sx21, sy01, sy11, sy21, sB1,
                               rloc, jh, lane, w, pcomb);
            if (lane < 8 && jh == 0) Af[base1 + rloc + rr] = LMU - __log2f(Sc);
        }
        POST(c1);
        // ---- stage A0 (posts were one compute phase ago) ----
        WAITB(c0, 32 * (2 * it + 1));
        ((float2*)sA0)[tid] = ((const float2*)(Af + base0))[tid];
        __syncthreads();
        // ---- gB0: g for batch0 (uses sx tables + sA0) ----
        {
            float Sc = sumpass(sy00, sy10, sy20, sx00, sx10, sx20, sA0,
                               rloc, jh, lane, w, pcomb);
            if (lane < 8 && jh == 0) Bf[base0 + rloc + rr] = LMU - __log2f(Sc);
        }
        POST(c0);
        // ---- stage A1 ----
        WAITB(c1, 32 * (2 * it + 1));
        ((float2*)sA1)[tid] = ((const float2*)(Af + base1))[tid];
        __syncthreads();
        // ---- gB1 ----
        {
            float Sc = sumpass(sy01, sy11, sy21, sx01, sx11, sx21, sA1,
                               rloc, jh, lane, w, pcomb);
            if (lane < 8 && jh == 0) Bf[base1 + rloc + rr] = LMU - __log2f(Sc);
        }
        POST(c1);
        // ---- stage B0 for next iteration ----
        WAITB(c0, 32 * (2 * it + 2));
        ((float2*)sB0)[tid] = ((const float2*)(Bf + base0))[tid];
        __syncthreads();
    }
    // final B1
    WAITB(c1, 32 * (2 * NITERS));
    ((float2*)sB1)[tid] = ((const float2*)(Bf + base1))[tid];
    __syncthreads();

    // ---- epilogue: own 64 rows of each batch, own j-half ----
    {
        float s = epil(sx00, sx10, sx20, sy00, sy10, sy20, sB0, sA0,
                       rloc, jh, lane)
                + epil(sx01, sx11, sx21, sy01, sy11, sy21, sB1, sA1,
                       rloc, jh, lane);
        #pragma unroll
        for (int m = 32; m > 0; m >>= 1) s += __shfl_xor(s, m, 64);
        if (lane == 0) wsum[w] = s;
        __syncthreads();
        if (tid == 0) {
            float t = 0.f;
            #pragma unroll
            for (int i = 0; i < 16; ++i) t += wsum[i];
            atomicAdd(out, t * (1.0f / (float)BB));
        }
    }
    #undef POST
    #undef WAITB
}

extern "C" void kernel_launch(void* const* d_in, const int* in_sizes, int n_in,
                              void* d_out, int out_size, void* d_ws, size_t ws_size,
                              hipStream_t stream) {
    const float* x = (const float*)d_in[0];
    const float* y = (const float*)d_in[1];
    float* out = (float*)d_out;
    char* ws = (char*)d_ws;

    int*   cntb = (int*)ws;                                  // 16 x 256 B
    float* Af   = (float*)(ws + 4096);                       // 128 KB
    float* Bf   = (float*)(ws + 4096 + (size_t)BB*NN*sizeof(float));

    hipMemsetAsync(cntb, 0, 4096, stream);
    hipMemsetAsync(out, 0, sizeof(float), stream);

    const size_t shmem = (size_t)16 * NN * sizeof(float);    // 128 KB
    hipFuncSetAttribute((const void*)emd_sinkhorn,
                        hipFuncAttributeMaxDynamicSharedMemorySize, (int)shmem);

    void* args[] = {(void*)&x, (void*)&y, (void*)&Af, (void*)&Bf,
                    (void*)&cntb, (void*)&out};
    hipError_t e = hipLaunchCooperativeKernel((const void*)emd_sinkhorn,
                                              dim3(256), dim3(1024),
                                              args, shmem, stream);
    if (e != hipSuccess) {
        hipLaunchKernelGGL(emd_sinkhorn, dim3(256), dim3(1024), shmem, stream,
                           x, y, Af, Bf, cntb, out);
    }
}